// Round 9
// baseline (83.296 us; speedup 1.0000x reference)
//
#include <hip/hip_runtime.h>
#include <math.h>

// Problem constants (setup_inputs: B=16, C=4, H=256, W=256, S=24)
constexpr int Hc = 256;
constexpr int Wc = 256;
constexpr float EPSf = 1e-6f;

__device__ __forceinline__ float comp(const float4& v, int p) {
    return p == 0 ? v.x : p == 1 ? v.y : p == 2 ? v.z : v.w;
}

// Branch-free acos for x in [0,1): Abramowitz-Stegun 4.4.45, |err|<=6.7e-5
// (tolerance 1.8e-2). Raw v_sqrt_f32, no libm fixup/branches.
__device__ __forceinline__ float fast_acos01(float x) {
    float t = __builtin_amdgcn_sqrtf(1.0f - x);
    float p = fmaf(fmaf(fmaf(-0.0187293f, x, 0.0742610f), x, -0.2121144f),
                   x, 1.5707288f);
    return t * p;
}

__device__ __forceinline__ float fast_sqrt(float x) {
    return __builtin_amdgcn_sqrtf(x);   // single v_sqrt_f32 (~2 ulp)
}

// R9: VMEM-instruction-issue theory. 24 VMEM/thread x 12.6M instr = ~49K/CU
// ~ observed kernel time; so cut VMEM instrs 24 -> 16 by moving the 8 scalar
// x-neighbor loads to the (idle) LDS pipe via __shfl_down. One wave = one
// full image row (64 lanes x 4 px = 256 = W), so all x-neighbors are
// in-wave; lane 63 edge folds to C.z in-register (exact under squaring).
// Locked-in from prior rounds: loads-first (R3), fast math (R7),
// partials + reduce-kernel epilogue (R4/R6 alternatives measured worse).
template<int S>
__global__ __launch_bounds__(256, 4) void sym_loss_main(
    const float* __restrict__ qp,
    const float* __restrict__ qt,
    const float* __restrict__ syms,
    float2* __restrict__ partial)
{
    int t    = blockIdx.x * 256 + threadIdx.x;
    int lane = t & 63;           // quad index within the row
    int row  = t >> 6;           // 0 .. B*H-1
    int b    = row >> 8;         // H = 256 rows per image
    int h    = row & (Hc - 1);
    int w0   = lane << 2;

    int idx0 = (b << 18) + (h << 8) + w0;   // channel-0 flat index
    // edge pad: squared differences make the direction sign irrelevant
    int dy = (h == Hc - 1) ? -Wc : Wc;      // wave-uniform

    // ---- phase 1: issue every global load (16 x dwordx4, nothing else) ----
    float4 Cp[4], Yp[4], Ct[4], Yt[4];
    #pragma unroll
    for (int c = 0; c < 4; ++c) {
        int idx = idx0 + (c << 16);
        Cp[c] = *(const float4*)(qp + idx);
        Yp[c] = *(const float4*)(qp + idx + dy);
        Ct[c] = *(const float4*)(qt + idx);
        Yt[c] = *(const float4*)(qt + idx + dy);
    }

    // ---- phase 2: gradient-magnitude term ----
    float gsum = 0.0f;
    #pragma unroll
    for (int c = 0; c < 4; ++c) {
        float4 C = Cp[c], Y = Yp[c], D = Ct[c], Z = Yt[c];

        // x-neighbor of element 3 via cross-lane (LDS pipe, not VMEM):
        // next lane's C.x; lane 63 (w=255 edge) folds to C.z (w=254).
        float nxp = __shfl_down(C.x, 1, 64);
        float nxt = __shfl_down(D.x, 1, 64);
        float px3 = (lane == 63) ? C.z : nxp;
        float tx3 = (lane == 63) ? D.z : nxt;

        float gx, gy, a, e;
        gx = C.y - C.x; gy = Y.x - C.x;
        a = fast_sqrt(fmaf(gx, gx, fmaf(gy, gy, EPSf)));
        gx = D.y - D.x; gy = Z.x - D.x;
        e = fast_sqrt(fmaf(gx, gx, fmaf(gy, gy, EPSf)));
        gsum += fabsf(a - e);

        gx = C.z - C.y; gy = Y.y - C.y;
        a = fast_sqrt(fmaf(gx, gx, fmaf(gy, gy, EPSf)));
        gx = D.z - D.y; gy = Z.y - D.y;
        e = fast_sqrt(fmaf(gx, gx, fmaf(gy, gy, EPSf)));
        gsum += fabsf(a - e);

        gx = C.w - C.z; gy = Y.z - C.z;
        a = fast_sqrt(fmaf(gx, gx, fmaf(gy, gy, EPSf)));
        gx = D.w - D.z; gy = Z.z - D.z;
        e = fast_sqrt(fmaf(gx, gx, fmaf(gy, gy, EPSf)));
        gsum += fabsf(a - e);

        gx = px3 - C.w; gy = Y.w - C.w;
        a = fast_sqrt(fmaf(gx, gx, fmaf(gy, gy, EPSf)));
        gx = tx3 - D.w; gy = Z.w - D.w;
        e = fast_sqrt(fmaf(gx, gx, fmaf(gy, gy, EPSf)));
        gsum += fabsf(a - e);
    }

    // ---- phase 3: per-pixel relative quaternion (vector part negated) ----
    float rw[4], nx[4], ny[4], nz[4];
    #pragma unroll
    for (int p = 0; p < 4; ++p) {
        float a0 = comp(Cp[0], p), a1 = comp(Cp[1], p),
              a2 = comp(Cp[2], p), a3 = comp(Cp[3], p);
        float b0 = comp(Ct[0], p), b1 = comp(Ct[1], p),
              b2 = comp(Ct[2], p), b3 = comp(Ct[3], p);

        float ss1 = fmaf(a0, a0, fmaf(a1, a1, fmaf(a2, a2, a3 * a3)));
        float ss2 = fmaf(b0, b0, fmaf(b1, b1, fmaf(b2, b2, b3 * b3)));
        float i1 = __builtin_amdgcn_rsqf(ss1);   // ss >> eps^2 here
        float i2 = __builtin_amdgcn_rsqf(ss2);
        float w1 = a0 * i1, x1 = a1 * i1, y1 = a2 * i1, z1 = a3 * i1;
        float w2 = b0 * i2, x2 = b1 * i2, y2 = b2 * i2, z2 = b3 * i2;

        rw[p] =  w2 * w1 + x2 * x1 + y2 * y1 + z2 * z1;
        float rx = -w2 * x1 + x2 * w1 - y2 * z1 + z2 * y1;
        float ry = -w2 * y1 + x2 * z1 + y2 * w1 - z2 * x1;
        float rz = -w2 * z1 - x2 * y1 + y2 * x1 + z2 * w1;
        nx[p] = -rx; ny[p] = -ry; nz[p] = -rz;   // signs [1,-1,-1,-1]
    }

    // ---- phase 4: sym search; wave-uniform scalar loads, fully unrolled ----
    const float4* __restrict__ sv4 = (const float4*)syms;
    float maxw[4] = {0.f, 0.f, 0.f, 0.f};
    #pragma unroll
    for (int s = 0; s < S; ++s) {
        float4 sv = sv4[s];
        #pragma unroll
        for (int p = 0; p < 4; ++p) {
            float d = fmaf(nz[p], sv.w,
                      fmaf(ny[p], sv.z,
                      fmaf(nx[p], sv.y, rw[p] * sv.x)));
            maxw[p] = fmaxf(maxw[p], fabsf(d));
        }
    }
    float rot = 0.0f;
    #pragma unroll
    for (int p = 0; p < 4; ++p)
        rot += fast_acos01(fminf(maxw[p], 1.0f - EPSf));
    // (x2 of 2*acos folded into reduce kernel's cRot)

    // ---- phase 5: block reduce -> one float2 partial per block ----
    #pragma unroll
    for (int off = 32; off > 0; off >>= 1) {
        rot  += __shfl_down(rot,  off, 64);
        gsum += __shfl_down(gsum, off, 64);
    }
    __shared__ float s_r[4], s_g[4];
    int wid = threadIdx.x >> 6;
    if ((threadIdx.x & 63) == 0) { s_r[wid] = rot; s_g[wid] = gsum; }
    __syncthreads();
    if (threadIdx.x == 0) {
        float2 o;
        o.x = s_r[0] + s_r[1] + s_r[2] + s_r[3];
        o.y = s_g[0] + s_g[1] + s_g[2] + s_g[3];
        partial[blockIdx.x] = o;
    }
}

// Generic-S fallback (runtime sym loop), R7 structure with scalar x-loads
__global__ __launch_bounds__(256) void sym_loss_generic(
    const float* __restrict__ qp,
    const float* __restrict__ qt,
    const float* __restrict__ syms,
    int S,
    float2* __restrict__ partial)
{
    int t    = blockIdx.x * 256 + threadIdx.x;
    int lane = t & 63;
    int row  = t >> 6;
    int b    = row >> 8;
    int h    = row & (Hc - 1);
    int w0   = lane << 2;
    int idx0 = (b << 18) + (h << 8) + w0;
    int dy = (h == Hc - 1) ? -Wc : Wc;
    int xo = (lane == 63) ? 2 : 4;

    float4 Cp[4], Yp[4], Ct[4], Yt[4];
    float  xp[4], xt[4];
    #pragma unroll
    for (int c = 0; c < 4; ++c) {
        int idx = idx0 + (c << 16);
        Cp[c] = *(const float4*)(qp + idx);
        Yp[c] = *(const float4*)(qp + idx + dy);
        xp[c] = qp[idx + xo];
        Ct[c] = *(const float4*)(qt + idx);
        Yt[c] = *(const float4*)(qt + idx + dy);
        xt[c] = qt[idx + xo];
    }
    float gsum = 0.0f;
    #pragma unroll
    for (int c = 0; c < 4; ++c) {
        float4 C = Cp[c], Y = Yp[c], D = Ct[c], Z = Yt[c];
        float gx, gy, a, e;
        gx = C.y - C.x; gy = Y.x - C.x;
        a = fast_sqrt(fmaf(gx, gx, fmaf(gy, gy, EPSf)));
        gx = D.y - D.x; gy = Z.x - D.x;
        e = fast_sqrt(fmaf(gx, gx, fmaf(gy, gy, EPSf)));
        gsum += fabsf(a - e);
        gx = C.z - C.y; gy = Y.y - C.y;
        a = fast_sqrt(fmaf(gx, gx, fmaf(gy, gy, EPSf)));
        gx = D.z - D.y; gy = Z.y - D.y;
        e = fast_sqrt(fmaf(gx, gx, fmaf(gy, gy, EPSf)));
        gsum += fabsf(a - e);
        gx = C.w - C.z; gy = Y.z - C.z;
        a = fast_sqrt(fmaf(gx, gx, fmaf(gy, gy, EPSf)));
        gx = D.w - D.z; gy = Z.z - D.z;
        e = fast_sqrt(fmaf(gx, gx, fmaf(gy, gy, EPSf)));
        gsum += fabsf(a - e);
        gx = xp[c] - C.w; gy = Y.w - C.w;
        a = fast_sqrt(fmaf(gx, gx, fmaf(gy, gy, EPSf)));
        gx = xt[c] - D.w; gy = Z.w - D.w;
        e = fast_sqrt(fmaf(gx, gx, fmaf(gy, gy, EPSf)));
        gsum += fabsf(a - e);
    }
    float rw[4], nx[4], ny[4], nz[4];
    #pragma unroll
    for (int p = 0; p < 4; ++p) {
        float a0 = comp(Cp[0], p), a1 = comp(Cp[1], p),
              a2 = comp(Cp[2], p), a3 = comp(Cp[3], p);
        float b0 = comp(Ct[0], p), b1 = comp(Ct[1], p),
              b2 = comp(Ct[2], p), b3 = comp(Ct[3], p);
        float ss1 = fmaf(a0, a0, fmaf(a1, a1, fmaf(a2, a2, a3 * a3)));
        float ss2 = fmaf(b0, b0, fmaf(b1, b1, fmaf(b2, b2, b3 * b3)));
        float i1 = __builtin_amdgcn_rsqf(ss1);
        float i2 = __builtin_amdgcn_rsqf(ss2);
        float w1 = a0 * i1, x1 = a1 * i1, y1 = a2 * i1, z1 = a3 * i1;
        float w2 = b0 * i2, x2 = b1 * i2, y2 = b2 * i2, z2 = b3 * i2;
        rw[p] =  w2 * w1 + x2 * x1 + y2 * y1 + z2 * z1;
        float rx = -w2 * x1 + x2 * w1 - y2 * z1 + z2 * y1;
        float ry = -w2 * y1 + x2 * z1 + y2 * w1 - z2 * x1;
        float rz = -w2 * z1 - x2 * y1 + y2 * x1 + z2 * w1;
        nx[p] = -rx; ny[p] = -ry; nz[p] = -rz;
    }
    const float4* __restrict__ sv4 = (const float4*)syms;
    float maxw[4] = {0.f, 0.f, 0.f, 0.f};
    for (int s = 0; s < S; ++s) {
        float4 sv = sv4[s];
        #pragma unroll
        for (int p = 0; p < 4; ++p) {
            float d = fmaf(nz[p], sv.w,
                      fmaf(ny[p], sv.z,
                      fmaf(nx[p], sv.y, rw[p] * sv.x)));
            maxw[p] = fmaxf(maxw[p], fabsf(d));
        }
    }
    float rot = 0.0f;
    #pragma unroll
    for (int p = 0; p < 4; ++p)
        rot += fast_acos01(fminf(maxw[p], 1.0f - EPSf));
    #pragma unroll
    for (int off = 32; off > 0; off >>= 1) {
        rot  += __shfl_down(rot,  off, 64);
        gsum += __shfl_down(gsum, off, 64);
    }
    __shared__ float s_r[4], s_g[4];
    int wid = threadIdx.x >> 6;
    if ((threadIdx.x & 63) == 0) { s_r[wid] = rot; s_g[wid] = gsum; }
    __syncthreads();
    if (threadIdx.x == 0) {
        float2 o;
        o.x = s_r[0] + s_r[1] + s_r[2] + s_r[3];
        o.y = s_g[0] + s_g[1] + s_g[2] + s_g[3];
        partial[blockIdx.x] = o;
    }
}

__global__ __launch_bounds__(256) void sym_loss_reduce(
    const float2* __restrict__ partial, int nblocks,
    float* __restrict__ out, double cRot, double cGrad)
{
    double r = 0.0, g = 0.0;
    for (int i = threadIdx.x; i < nblocks; i += 256) {
        float2 p = partial[i];
        r += (double)p.x;
        g += (double)p.y;
    }
    #pragma unroll
    for (int off = 32; off > 0; off >>= 1) {
        r += __shfl_down(r, off, 64);
        g += __shfl_down(g, off, 64);
    }
    __shared__ double s_r[4], s_g[4];
    int wid = threadIdx.x >> 6;
    if ((threadIdx.x & 63) == 0) { s_r[wid] = r; s_g[wid] = g; }
    __syncthreads();
    if (threadIdx.x == 0) {
        double rr = s_r[0] + s_r[1] + s_r[2] + s_r[3];
        double gg = s_g[0] + s_g[1] + s_g[2] + s_g[3];
        out[0] = (float)(rr * cRot + gg * cGrad);
    }
}

extern "C" void kernel_launch(void* const* d_in, const int* in_sizes, int n_in,
                              void* d_out, int out_size, void* d_ws, size_t ws_size,
                              hipStream_t stream)
{
    const float* qp   = (const float*)d_in[0];
    const float* qt   = (const float*)d_in[1];
    const float* syms = (const float*)d_in[2];

    int S  = in_sizes[2] / 4;        // 24
    int NP = in_sizes[0] / 4;        // B*H*W = 1,048,576 pixels
    int nblocks = (NP / 4) / 256;    // 1024

    float2* partial = (float2*)d_ws; // every slot written each call

    // loss = (2*sum_acos)/NP + 0.05*sum_grad/(4*NP)
    double cRot  = 2.0 / (double)NP;
    double cGrad = 0.05 / ((double)NP * 4.0);

    if (S == 24) {
        sym_loss_main<24><<<nblocks, 256, 0, stream>>>(qp, qt, syms, partial);
    } else {
        sym_loss_generic<<<nblocks, 256, 0, stream>>>(qp, qt, syms, S, partial);
    }

    sym_loss_reduce<<<1, 256, 0, stream>>>(partial, nblocks, (float*)d_out,
                                           cRot, cGrad);
}

// Round 10
// 81.516 us; speedup vs baseline: 1.0218x; 1.0218x over previous
//
#include <hip/hip_runtime.h>
#include <math.h>

// Problem constants (setup_inputs: B=16, C=4, H=256, W=256, S=24)
constexpr int Hc = 256;
constexpr int Wc = 256;
constexpr float EPSf = 1e-6f;

__device__ __forceinline__ float comp(const float4& v, int p) {
    return p == 0 ? v.x : p == 1 ? v.y : p == 2 ? v.z : v.w;
}

// Branch-free acos for x in [0,1): Abramowitz-Stegun 4.4.45, |err|<=6.7e-5
// (tolerance 1.8e-2). Raw v_sqrt_f32, no libm fixup/branches.
__device__ __forceinline__ float fast_acos01(float x) {
    float t = __builtin_amdgcn_sqrtf(1.0f - x);
    float p = fmaf(fmaf(fmaf(-0.0187293f, x, 0.0742610f), x, -0.2121144f),
                   x, 1.5707288f);
    return t * p;
}

__device__ __forceinline__ float fast_sqrt(float x) {
    return __builtin_amdgcn_sqrtf(x);   // single v_sqrt_f32 (~2 ulp)
}

// Phases 2-4 for one 4-px quad tile (R9-verified math).
template<int S>
__device__ __forceinline__ void process_tile(
    int lane,
    const float4 Cp[4], const float4 Yp[4],
    const float4 Ct[4], const float4 Yt[4],
    const float* __restrict__ syms,
    float& gsum, float& rot)
{
    // gradient-magnitude term
    #pragma unroll
    for (int c = 0; c < 4; ++c) {
        float4 C = Cp[c], Y = Yp[c], D = Ct[c], Z = Yt[c];
        // x-neighbor of element 3 via cross-lane; lane 63 (w=255 edge)
        // folds to C.z (w=254) — exact under squaring.
        float nxp = __shfl_down(C.x, 1, 64);
        float nxt = __shfl_down(D.x, 1, 64);
        float px3 = (lane == 63) ? C.z : nxp;
        float tx3 = (lane == 63) ? D.z : nxt;

        float gx, gy, a, e;
        gx = C.y - C.x; gy = Y.x - C.x;
        a = fast_sqrt(fmaf(gx, gx, fmaf(gy, gy, EPSf)));
        gx = D.y - D.x; gy = Z.x - D.x;
        e = fast_sqrt(fmaf(gx, gx, fmaf(gy, gy, EPSf)));
        gsum += fabsf(a - e);

        gx = C.z - C.y; gy = Y.y - C.y;
        a = fast_sqrt(fmaf(gx, gx, fmaf(gy, gy, EPSf)));
        gx = D.z - D.y; gy = Z.y - D.y;
        e = fast_sqrt(fmaf(gx, gx, fmaf(gy, gy, EPSf)));
        gsum += fabsf(a - e);

        gx = C.w - C.z; gy = Y.z - C.z;
        a = fast_sqrt(fmaf(gx, gx, fmaf(gy, gy, EPSf)));
        gx = D.w - D.z; gy = Z.z - D.z;
        e = fast_sqrt(fmaf(gx, gx, fmaf(gy, gy, EPSf)));
        gsum += fabsf(a - e);

        gx = px3 - C.w; gy = Y.w - C.w;
        a = fast_sqrt(fmaf(gx, gx, fmaf(gy, gy, EPSf)));
        gx = tx3 - D.w; gy = Z.w - D.w;
        e = fast_sqrt(fmaf(gx, gx, fmaf(gy, gy, EPSf)));
        gsum += fabsf(a - e);
    }

    // per-pixel relative quaternion (vector part negated)
    float rw[4], nx[4], ny[4], nz[4];
    #pragma unroll
    for (int p = 0; p < 4; ++p) {
        float a0 = comp(Cp[0], p), a1 = comp(Cp[1], p),
              a2 = comp(Cp[2], p), a3 = comp(Cp[3], p);
        float b0 = comp(Ct[0], p), b1 = comp(Ct[1], p),
              b2 = comp(Ct[2], p), b3 = comp(Ct[3], p);

        float ss1 = fmaf(a0, a0, fmaf(a1, a1, fmaf(a2, a2, a3 * a3)));
        float ss2 = fmaf(b0, b0, fmaf(b1, b1, fmaf(b2, b2, b3 * b3)));
        float i1 = __builtin_amdgcn_rsqf(ss1);   // ss >> eps^2 here
        float i2 = __builtin_amdgcn_rsqf(ss2);
        float w1 = a0 * i1, x1 = a1 * i1, y1 = a2 * i1, z1 = a3 * i1;
        float w2 = b0 * i2, x2 = b1 * i2, y2 = b2 * i2, z2 = b3 * i2;

        rw[p] =  w2 * w1 + x2 * x1 + y2 * y1 + z2 * z1;
        float rx = -w2 * x1 + x2 * w1 - y2 * z1 + z2 * y1;
        float ry = -w2 * y1 + x2 * z1 + y2 * w1 - z2 * x1;
        float rz = -w2 * z1 - x2 * y1 + y2 * x1 + z2 * w1;
        nx[p] = -rx; ny[p] = -ry; nz[p] = -rz;   // signs [1,-1,-1,-1]
    }

    // sym search; wave-uniform scalar loads, fully unrolled
    const float4* __restrict__ sv4 = (const float4*)syms;
    float maxw[4] = {0.f, 0.f, 0.f, 0.f};
    #pragma unroll
    for (int s = 0; s < S; ++s) {
        float4 sv = sv4[s];
        #pragma unroll
        for (int p = 0; p < 4; ++p) {
            float d = fmaf(nz[p], sv.w,
                      fmaf(ny[p], sv.z,
                      fmaf(nx[p], sv.y, rw[p] * sv.x)));
            maxw[p] = fmaxf(maxw[p], fabsf(d));
        }
    }
    #pragma unroll
    for (int p = 0; p < 4; ++p)
        rot += fast_acos01(fminf(maxw[p], 1.0f - EPSf));
}

// R10: per-wave MLP. 512 blocks (exactly 2/CU, tail-free); each thread owns
// TWO 4-px quads (t and t+NT) and ALL 32 dwordx4 loads are issued before any
// compute — tile-1 loads stay in flight over tile-0 compute (incremental
// vmcnt). Prior probes: VALU cut (R7) -1us, waves x2 (R8) -1us, VMEM cut
// (R9) ~0 — ILP/MLP is the one untried mechanism. Locked: shfl x-neighbor,
// fast math, partials + reduce-kernel epilogue (R4/R6 alternatives worse).
template<int S>
__global__ __launch_bounds__(256) void sym_loss_main(
    const float* __restrict__ qp,
    const float* __restrict__ qt,
    const float* __restrict__ syms,
    float2* __restrict__ partial)
{
    const int nt   = gridDim.x << 8;            // total threads (= #quads/2)
    const int t0   = (blockIdx.x << 8) + threadIdx.x;
    const int lane = t0 & 63;                   // nt % 64 == 0 -> same both tiles

    const int q1   = t0 + nt;                   // second tile's quad index
    int row0 = t0 >> 6,        row1 = q1 >> 6;
    int b0   = row0 >> 8,      b1   = row1 >> 8;
    int h0   = row0 & (Hc-1),  h1   = row1 & (Hc-1);
    int w0   = lane << 2;
    int idxA = (b0 << 18) + (h0 << 8) + w0;     // channel-0 flat indices
    int idxB = (b1 << 18) + (h1 << 8) + w0;
    int dyA  = (h0 == Hc-1) ? -Wc : Wc;         // edge pad, sign-free squared
    int dyB  = (h1 == Hc-1) ? -Wc : Wc;

    // ---- issue ALL 32 global loads (2 tiles x 16 dwordx4) ----
    float4 Cp0[4], Yp0[4], Ct0[4], Yt0[4];
    float4 Cp1[4], Yp1[4], Ct1[4], Yt1[4];
    #pragma unroll
    for (int c = 0; c < 4; ++c) {
        int ia = idxA + (c << 16), ib = idxB + (c << 16);
        Cp0[c] = *(const float4*)(qp + ia);
        Yp0[c] = *(const float4*)(qp + ia + dyA);
        Ct0[c] = *(const float4*)(qt + ia);
        Yt0[c] = *(const float4*)(qt + ia + dyA);
        Cp1[c] = *(const float4*)(qp + ib);
        Yp1[c] = *(const float4*)(qp + ib + dyB);
        Ct1[c] = *(const float4*)(qt + ib);
        Yt1[c] = *(const float4*)(qt + ib + dyB);
    }

    float gsum = 0.0f, rot = 0.0f;
    process_tile<S>(lane, Cp0, Yp0, Ct0, Yt0, syms, gsum, rot);
    process_tile<S>(lane, Cp1, Yp1, Ct1, Yt1, syms, gsum, rot);

    // ---- block reduce -> one float2 partial per block ----
    #pragma unroll
    for (int off = 32; off > 0; off >>= 1) {
        rot  += __shfl_down(rot,  off, 64);
        gsum += __shfl_down(gsum, off, 64);
    }
    __shared__ float s_r[4], s_g[4];
    int wid = threadIdx.x >> 6;
    if ((threadIdx.x & 63) == 0) { s_r[wid] = rot; s_g[wid] = gsum; }
    __syncthreads();
    if (threadIdx.x == 0) {
        float2 o;
        o.x = s_r[0] + s_r[1] + s_r[2] + s_r[3];
        o.y = s_g[0] + s_g[1] + s_g[2] + s_g[3];
        partial[blockIdx.x] = o;
    }
}

// Generic-S fallback (runtime sym loop), R9 single-tile structure
__global__ __launch_bounds__(256) void sym_loss_generic(
    const float* __restrict__ qp,
    const float* __restrict__ qt,
    const float* __restrict__ syms,
    int S,
    float2* __restrict__ partial)
{
    int t    = blockIdx.x * 256 + threadIdx.x;
    int lane = t & 63;
    int row  = t >> 6;
    int b    = row >> 8;
    int h    = row & (Hc - 1);
    int w0   = lane << 2;
    int idx0 = (b << 18) + (h << 8) + w0;
    int dy = (h == Hc - 1) ? -Wc : Wc;
    int xo = (lane == 63) ? 2 : 4;

    float4 Cp[4], Yp[4], Ct[4], Yt[4];
    float  xp[4], xt[4];
    #pragma unroll
    for (int c = 0; c < 4; ++c) {
        int idx = idx0 + (c << 16);
        Cp[c] = *(const float4*)(qp + idx);
        Yp[c] = *(const float4*)(qp + idx + dy);
        xp[c] = qp[idx + xo];
        Ct[c] = *(const float4*)(qt + idx);
        Yt[c] = *(const float4*)(qt + idx + dy);
        xt[c] = qt[idx + xo];
    }
    float gsum = 0.0f;
    #pragma unroll
    for (int c = 0; c < 4; ++c) {
        float4 C = Cp[c], Y = Yp[c], D = Ct[c], Z = Yt[c];
        float gx, gy, a, e;
        gx = C.y - C.x; gy = Y.x - C.x;
        a = fast_sqrt(fmaf(gx, gx, fmaf(gy, gy, EPSf)));
        gx = D.y - D.x; gy = Z.x - D.x;
        e = fast_sqrt(fmaf(gx, gx, fmaf(gy, gy, EPSf)));
        gsum += fabsf(a - e);
        gx = C.z - C.y; gy = Y.y - C.y;
        a = fast_sqrt(fmaf(gx, gx, fmaf(gy, gy, EPSf)));
        gx = D.z - D.y; gy = Z.y - D.y;
        e = fast_sqrt(fmaf(gx, gx, fmaf(gy, gy, EPSf)));
        gsum += fabsf(a - e);
        gx = C.w - C.z; gy = Y.z - C.z;
        a = fast_sqrt(fmaf(gx, gx, fmaf(gy, gy, EPSf)));
        gx = D.w - D.z; gy = Z.z - D.z;
        e = fast_sqrt(fmaf(gx, gx, fmaf(gy, gy, EPSf)));
        gsum += fabsf(a - e);
        gx = xp[c] - C.w; gy = Y.w - C.w;
        a = fast_sqrt(fmaf(gx, gx, fmaf(gy, gy, EPSf)));
        gx = xt[c] - D.w; gy = Z.w - D.w;
        e = fast_sqrt(fmaf(gx, gx, fmaf(gy, gy, EPSf)));
        gsum += fabsf(a - e);
    }
    float rw[4], nx[4], ny[4], nz[4];
    #pragma unroll
    for (int p = 0; p < 4; ++p) {
        float a0 = comp(Cp[0], p), a1 = comp(Cp[1], p),
              a2 = comp(Cp[2], p), a3 = comp(Cp[3], p);
        float b0 = comp(Ct[0], p), b1 = comp(Ct[1], p),
              b2 = comp(Ct[2], p), b3 = comp(Ct[3], p);
        float ss1 = fmaf(a0, a0, fmaf(a1, a1, fmaf(a2, a2, a3 * a3)));
        float ss2 = fmaf(b0, b0, fmaf(b1, b1, fmaf(b2, b2, b3 * b3)));
        float i1 = __builtin_amdgcn_rsqf(ss1);
        float i2 = __builtin_amdgcn_rsqf(ss2);
        float w1 = a0 * i1, x1 = a1 * i1, y1 = a2 * i1, z1 = a3 * i1;
        float w2 = b0 * i2, x2 = b1 * i2, y2 = b2 * i2, z2 = b3 * i2;
        rw[p] =  w2 * w1 + x2 * x1 + y2 * y1 + z2 * z1;
        float rx = -w2 * x1 + x2 * w1 - y2 * z1 + z2 * y1;
        float ry = -w2 * y1 + x2 * z1 + y2 * w1 - z2 * x1;
        float rz = -w2 * z1 - x2 * y1 + y2 * x1 + z2 * w1;
        nx[p] = -rx; ny[p] = -ry; nz[p] = -rz;
    }
    const float4* __restrict__ sv4 = (const float4*)syms;
    float maxw[4] = {0.f, 0.f, 0.f, 0.f};
    for (int s = 0; s < S; ++s) {
        float4 sv = sv4[s];
        #pragma unroll
        for (int p = 0; p < 4; ++p) {
            float d = fmaf(nz[p], sv.w,
                      fmaf(ny[p], sv.z,
                      fmaf(nx[p], sv.y, rw[p] * sv.x)));
            maxw[p] = fmaxf(maxw[p], fabsf(d));
        }
    }
    float rot = 0.0f;
    #pragma unroll
    for (int p = 0; p < 4; ++p)
        rot += fast_acos01(fminf(maxw[p], 1.0f - EPSf));
    #pragma unroll
    for (int off = 32; off > 0; off >>= 1) {
        rot  += __shfl_down(rot,  off, 64);
        gsum += __shfl_down(gsum, off, 64);
    }
    __shared__ float s_r[4], s_g[4];
    int wid = threadIdx.x >> 6;
    if ((threadIdx.x & 63) == 0) { s_r[wid] = rot; s_g[wid] = gsum; }
    __syncthreads();
    if (threadIdx.x == 0) {
        float2 o;
        o.x = s_r[0] + s_r[1] + s_r[2] + s_r[3];
        o.y = s_g[0] + s_g[1] + s_g[2] + s_g[3];
        partial[blockIdx.x] = o;
    }
}

__global__ __launch_bounds__(256) void sym_loss_reduce(
    const float2* __restrict__ partial, int nblocks,
    float* __restrict__ out, double cRot, double cGrad)
{
    double r = 0.0, g = 0.0;
    for (int i = threadIdx.x; i < nblocks; i += 256) {
        float2 p = partial[i];
        r += (double)p.x;
        g += (double)p.y;
    }
    #pragma unroll
    for (int off = 32; off > 0; off >>= 1) {
        r += __shfl_down(r, off, 64);
        g += __shfl_down(g, off, 64);
    }
    __shared__ double s_r[4], s_g[4];
    int wid = threadIdx.x >> 6;
    if ((threadIdx.x & 63) == 0) { s_r[wid] = r; s_g[wid] = g; }
    __syncthreads();
    if (threadIdx.x == 0) {
        double rr = s_r[0] + s_r[1] + s_r[2] + s_r[3];
        double gg = s_g[0] + s_g[1] + s_g[2] + s_g[3];
        out[0] = (float)(rr * cRot + gg * cGrad);
    }
}

extern "C" void kernel_launch(void* const* d_in, const int* in_sizes, int n_in,
                              void* d_out, int out_size, void* d_ws, size_t ws_size,
                              hipStream_t stream)
{
    const float* qp   = (const float*)d_in[0];
    const float* qt   = (const float*)d_in[1];
    const float* syms = (const float*)d_in[2];

    int S  = in_sizes[2] / 4;        // 24
    int NP = in_sizes[0] / 4;        // B*H*W = 1,048,576 pixels

    float2* partial = (float2*)d_ws; // every slot written each call

    // loss = (2*sum_acos)/NP + 0.05*sum_grad/(4*NP)
    double cRot  = 2.0 / (double)NP;
    double cGrad = 0.05 / ((double)NP * 4.0);

    int nblocks;
    if (S == 24) {
        nblocks = NP / 2048;         // 2 tiles x 4 px x 256 thr = 512 blocks
        sym_loss_main<24><<<nblocks, 256, 0, stream>>>(qp, qt, syms, partial);
    } else {
        nblocks = (NP / 4) / 256;
        sym_loss_generic<<<nblocks, 256, 0, stream>>>(qp, qt, syms, S, partial);
    }

    sym_loss_reduce<<<1, 256, 0, stream>>>(partial, nblocks, (float*)d_out,
                                           cRot, cGrad);
}